// Round 11
// baseline (278.217 us; speedup 1.0000x reference)
//
#include <hip/hip_runtime.h>
#include <math.h>

#define N_NODES 100000
#define N_EDGES 3200000
#define E_TOT   (N_EDGES + N_NODES)
#define F_IN    128
#define H1      16
#define H2      8
#define NEG     0.2f
#define LOG2E   1.4426950408889634f
#define NBUCKET ((N_NODES + 255) >> 8)             // 391 buckets of 256 nodes
#define NCHUNK  512
#define CE      ((N_EDGES + NCHUNK - 1) / NCHUNK)  // 6250 edges per chunk (even)

typedef _Float16 half2v __attribute__((ext_vector_type(2)));
typedef _Float16 half8v __attribute__((ext_vector_type(8)));

// ---- layer-1 projection -> packed g1 (64B/node: 16 fp16 h ; fp32 es*log2e).
// Launched LAST before agg1 so g1 stays warm in L2 (R10 counter-verified:
// running CSR traffic after this costs +43MB agg1 fetch / +12us). ----
__global__ __launch_bounds__(256) void k1_xw(
        const float* __restrict__ x, const float* __restrict__ W1,
        const float* __restrict__ a1s, const float* __restrict__ a1d,
        char* __restrict__ g1, float* __restrict__ e1d) {
    __shared__ float w1s[F_IN * H1];     // 8 KB
    __shared__ float xs[16 * 132];       // padded stride 132 -> conflict-free
    __shared__ float a1ss[H1], a1ds[H1];
    const int tid = threadIdx.x;
    for (int i = tid; i < F_IN * H1; i += 256) w1s[i] = W1[i];
    if (tid < H1) { a1ss[tid] = a1s[tid]; a1ds[tid] = a1d[tid]; }
    const int rowbase = blockIdx.x * 16;
    #pragma unroll
    for (int i = 0; i < 2; i++) {
        int q = tid + i * 256;
        int r = q >> 5, c = q & 31;
        float4 v = *(const float4*)(x + (size_t)(rowbase + r) * F_IN + c * 4);
        *(float4*)(xs + r * 132 + c * 4) = v;
    }
    __syncthreads();
    const int g = tid >> 4, j = tid & 15;
    const float* xrow = xs + g * 132;
    float acc = 0.f;
    #pragma unroll 8
    for (int k = 0; k < F_IN; k++) acc += xrow[k] * w1s[k * H1 + j];
    const int row = rowbase + g;
    char* grow = g1 + (size_t)row * 64;
    ((_Float16*)grow)[j] = (_Float16)acc;
    float ps = acc * a1ss[j];
    float pd = acc * a1ds[j];
    #pragma unroll
    for (int m = 8; m >= 1; m >>= 1) {
        ps += __shfl_xor(ps, m, 16);
        pd += __shfl_xor(pd, m, 16);
    }
    if (j == 0) { *(float*)(grow + 32) = ps * LOG2E; e1d[row] = pd * LOG2E; }
}

// ---- counting-sort CSR build (LDS atomics only) ----

__global__ __launch_bounds__(256) void k_count(const int2* __restrict__ ei,
                                               int* __restrict__ counts) {
    __shared__ int hist[NBUCKET];
    for (int i = threadIdx.x; i < NBUCKET; i += 256) hist[i] = 0;
    __syncthreads();
    const int b = blockIdx.x;
    const int4* p4 = (const int4*)(ei + b * CE);   // 2 edges per int4
    for (int q = threadIdx.x; q < CE / 2; q += 256) {
        int4 v = p4[q];
        atomicAdd(&hist[v.y >> 8], 1);
        atomicAdd(&hist[v.w >> 8], 1);
    }
    __syncthreads();
    for (int i = threadIdx.x; i < NBUCKET; i += 256)
        counts[i * NCHUNK + b] = hist[i];
}

// per-bucket exclusive scan of counts across chunks; bucket totals -> btot
__global__ __launch_bounds__(512) void k_scanA(int* __restrict__ counts,
                                               int* __restrict__ btot) {
    __shared__ int lds[NCHUNK];
    const int k = blockIdx.x, t = threadIdx.x;
    int v = counts[k * NCHUNK + t];
    lds[t] = v;
    __syncthreads();
    for (int off = 1; off < NCHUNK; off <<= 1) {
        int u = (t >= off) ? lds[t - off] : 0;
        __syncthreads();
        lds[t] += u;
        __syncthreads();
    }
    counts[k * NCHUNK + t] = lds[t] - v;   // exclusive within bucket
    if (t == NCHUNK - 1) btot[k] = lds[t];
}

// scatter edges into bucket segments; bucket bases computed in-block from btot
// (paired Hillis-Steele over 512-padded 391 entries) -- no separate scanB.
__global__ __launch_bounds__(256) void k_reorder(const int2* __restrict__ ei,
                                                 const int* __restrict__ counts,
                                                 const int* __restrict__ btot,
                                                 int* __restrict__ pairs) {
    __shared__ int bb[512];
    __shared__ int ps[256];
    __shared__ int cur[NBUCKET];
    const int b = blockIdx.x, tid = threadIdx.x;
    bb[tid]       = (tid < NBUCKET) ? btot[tid] : 0;
    bb[tid + 256] = (tid + 256 < NBUCKET) ? btot[tid + 256] : 0;
    __syncthreads();
    const int lo = bb[2 * tid], hi = bb[2 * tid + 1];
    ps[tid] = lo + hi;
    __syncthreads();
    for (int off = 1; off < 256; off <<= 1) {
        int u = (tid >= off) ? ps[tid - off] : 0;
        __syncthreads();
        ps[tid] += u;
        __syncthreads();
    }
    const int ep = ps[tid] - (lo + hi);    // exclusive pair prefix
    __syncthreads();
    bb[2 * tid]     = ep;                  // bb[i] = exclusive prefix of btot
    bb[2 * tid + 1] = ep + lo;
    __syncthreads();
    for (int i = tid; i < NBUCKET; i += 256)
        cur[i] = bb[i] + counts[i * NCHUNK + b];
    __syncthreads();
    const int4* p4 = (const int4*)(ei + b * CE);   // 2 edges per int4
    for (int q = tid; q < CE / 2; q += 256) {
        int4 v = p4[q];
        int pos0 = atomicAdd(&cur[v.y >> 8], 1);   // LDS atomic only
        pairs[pos0] = (v.x << 8) | (v.y & 255);
        int pos1 = atomicAdd(&cur[v.w >> 8], 1);
        pairs[pos1] = (v.z << 8) | (v.w & 255);
    }
}

// per-bucket CSR finalize; bucket base = block-reduce partial sum over btot
__global__ __launch_bounds__(256) void k_csr(const int* __restrict__ pairs,
                                             const int* __restrict__ btot,
                                             int* __restrict__ rowg,
                                             int* __restrict__ degg,
                                             int* __restrict__ sorted_src) {
    __shared__ int deg[256], scn[256], cur[256], red[256];
    const int k = blockIdx.x, t = threadIdx.x;
    const int n0 = k << 8;
    const int nn = min(256, N_NODES - n0);
    // bucket edge base = sum btot[0..k)
    int part = 0;
    for (int i = t; i < k; i += 256) part += btot[i];
    red[t] = part;
    deg[t] = 0;
    __syncthreads();
    for (int off = 128; off >= 1; off >>= 1) {
        if (t < off) red[t] += red[t + off];
        __syncthreads();
    }
    const int ebeg = red[0];
    const int eend = ebeg + btot[k];
    for (int e = ebeg + t; e < eend; e += 256)
        atomicAdd(&deg[pairs[e] & 255], 1);
    __syncthreads();
    int v = (t < nn) ? deg[t] : 0;
    scn[t] = v;
    __syncthreads();
    for (int off = 1; off < 256; off <<= 1) {
        int u = (t >= off) ? scn[t - off] : 0;
        __syncthreads();
        scn[t] += u;
        __syncthreads();
    }
    int excl = scn[t] - v;
    if (t < nn) {
        int r = ebeg + excl + n0 + t;   // + self-loops of all preceding nodes
        rowg[n0 + t] = r;
        degg[n0 + t] = v + 1;
        sorted_src[r] = n0 + t;         // self-loop occupies slot 0
        cur[t] = r + 1;
    }
    __syncthreads();
    for (int e = ebeg + t; e < eend; e += 256) {
        int p = pairs[e];
        int pos = atomicAdd(&cur[p & 255], 1);   // LDS atomic only
        sorted_src[pos] = p >> 8;
    }
}

// ---- node-parallel softmax aggregation over packed gather tables ----
// (FROZEN: measured 41.1us agg1 in R8. One random 64B line per edge; U=16
// outstanding gathers; log2e-prescaled logits -> exp2.)
template <int LPN, int U, int ROWB, int ESOFF, bool LAYER2>
__global__ __launch_bounds__(256) void k_agg(
        const int* __restrict__ row, const int* __restrict__ deg,
        const int* __restrict__ sorted_src,
        const float* __restrict__ ed, const char* __restrict__ gtab,
        const float* __restrict__ b,
        const float* __restrict__ W2, const float* __restrict__ a2s,
        const float* __restrict__ a2d,
        char* __restrict__ g2out, float* __restrict__ e2d_out,
        const float* __restrict__ Wf, const float* __restrict__ bf,
        float* __restrict__ out) {
    __shared__ float w2s[H1 * H2];
    __shared__ float a2ss[H2], a2ds[H2];
    if (!LAYER2) {
        for (int i = threadIdx.x; i < H1 * H2; i += 256) w2s[i] = W2[i];
        if (threadIdx.x < H2) { a2ss[threadIdx.x] = a2s[threadIdx.x];
                                a2ds[threadIdx.x] = a2d[threadIdx.x]; }
        __syncthreads();
    }
    const int sub = threadIdx.x & (LPN - 1);
    const int node = (blockIdx.x * 256 + threadIdx.x) / LPN;
    if (node >= N_NODES) return;
    const int beg = row[node];
    const int cnt = deg[node];            // >= 1 (self-loop)
    const float edv = ed[node];           // pre-scaled by log2(e)
    float2 acc = make_float2(0.f, 0.f);
    float s = 0.f;
    int srcs[U];
    #pragma unroll
    for (int i = 0; i < U; i++) srcs[i] = sorted_src[beg + (i < cnt ? i : 0)];
    for (int t0 = 0; t0 < cnt; t0 += U) {
        float evs[U];
        half2v hvs[U];
        // issue gathers for the current batch (one 64B line per edge)
        #pragma unroll
        for (int i = 0; i < U; i++) {
            const char* rp = gtab + (unsigned)srcs[i] * ROWB;
            hvs[i] = *(const half2v*)(rp + sub * 4);
            evs[i] = *(const float*)(rp + ESOFF);   // same line as h -> free
        }
        // prefetch next batch's indices while gathers are in flight
        int nsrcs[U];
        #pragma unroll
        for (int i = 0; i < U; i++) {
            int idx = t0 + U + i;
            nsrcs[i] = sorted_src[beg + (idx < cnt ? idx : 0)];
        }
        #pragma unroll
        for (int i = 0; i < U; i++) {
            if (t0 + i < cnt) {
                float k = evs[i] + edv;
                k = fmaxf(k, NEG * k);              // leaky_relu (scale-invariant)
                float p = __builtin_amdgcn_exp2f(k);
                s += p;
                acc.x += p * (float)hvs[i].x;
                acc.y += p * (float)hvs[i].y;
            }
        }
        #pragma unroll
        for (int i = 0; i < U; i++) srcs[i] = nsrcs[i];
    }
    const float inv = 1.f / s;
    const float2 bv = ((const float2*)b)[sub];
    float2 o;
    o.x = fmaxf(acc.x * inv + bv.x, 0.f);
    o.y = fmaxf(acc.y * inv + bv.y, 0.f);
    if (!LAYER2) {
        // fused h2 = relu(h1) @ W2 ; e2s ; e2d  (lane sub owns h1 rows 2sub, 2sub+1)
        float p2[H2];
        const float* w0 = w2s + (2 * sub) * H2;
        const float* w1 = w2s + (2 * sub + 1) * H2;
        #pragma unroll
        for (int i = 0; i < H2; i++) p2[i] = o.x * w0[i] + o.y * w1[i];
        #pragma unroll
        for (int i = 0; i < H2; i++) {
            p2[i] += __shfl_xor(p2[i], 1);
            p2[i] += __shfl_xor(p2[i], 2);
            p2[i] += __shfl_xor(p2[i], 4);
        }
        float es2 = 0.f, ed2 = 0.f;
        #pragma unroll
        for (int i = 0; i < H2; i++) { es2 += p2[i] * a2ss[i]; ed2 += p2[i] * a2ds[i]; }
        char* orow = g2out + (size_t)node * 32;
        if (sub == 0) {
            half8v h8;
            #pragma unroll
            for (int i = 0; i < H2; i++) h8[i] = (_Float16)p2[i];
            *(half8v*)orow = h8;                      // bytes 0..15
        } else if (sub == 1) {
            *(float*)(orow + 16) = es2 * LOG2E;       // es2 in the same 32B row
        } else if (sub == 2) {
            e2d_out[node] = ed2 * LOG2E;
        }
    } else {
        // final head: out = relu(h2agg) . Wf + bf  (lane sub owns h2 2sub, 2sub+1)
        const float2 wv = ((const float2*)Wf)[sub];
        float r = o.x * wv.x + o.y * wv.y;
        r += __shfl_xor(r, 1);
        r += __shfl_xor(r, 2);
        if (sub == 0) out[node] = r + bf[0];
    }
}

extern "C" void kernel_launch(void* const* d_in, const int* in_sizes, int n_in,
                              void* d_out, int out_size, void* d_ws, size_t ws_size,
                              hipStream_t stream) {
    const float* x    = (const float*)d_in[0];
    const int2*  ei   = (const int2*)d_in[1];   // int32 pairs [src,dst]
    const float* W1   = (const float*)d_in[2];
    const float* a1s  = (const float*)d_in[3];
    const float* a1d  = (const float*)d_in[4];
    const float* b1   = (const float*)d_in[5];
    const float* W2   = (const float*)d_in[6];
    const float* a2s  = (const float*)d_in[7];
    const float* a2d  = (const float*)d_in[8];
    const float* b2   = (const float*)d_in[9];
    const float* Wf   = (const float*)d_in[10];
    const float* bf   = (const float*)d_in[11];
    float* out = (float*)d_out;

    // workspace layout; pairs region (12.8 MB) is dead after k_csr and hosts
    // g2 (3.2) + e2d (0.4); g1 (6.4) + e1d live separately
    char* wp = (char*)d_ws;
    int* sorted_src = (int*)wp;   wp += sizeof(int) * (size_t)E_TOT;
    char* pairs_region = wp;      wp += sizeof(int) * (size_t)N_EDGES;   // 12.8 MB
    int* counts     = (int*)wp;   wp += sizeof(int) * (size_t)NBUCKET * NCHUNK;
    int* btot       = (int*)wp;   wp += sizeof(int) * (NBUCKET + 1);
    int* degg       = (int*)wp;   wp += sizeof(int) * N_NODES;
    int* rowg       = (int*)wp;   wp += sizeof(int) * N_NODES;
    char* g1        = wp;         wp += (size_t)64 * N_NODES;            // 6.4 MB
    float* e1d      = (float*)wp; wp += sizeof(float) * N_NODES;

    int*   pairs = (int*)pairs_region;
    char*  g2    = pairs_region;                              // 32B * N = 3.2 MB
    float* e2d   = (float*)(g2 + (size_t)32 * N_NODES);       // 0.4 MB

    // CSR build first (its streaming traffic must not evict g1)
    k_count<<<NCHUNK, 256, 0, stream>>>(ei, counts);
    k_scanA<<<NBUCKET, 512, 0, stream>>>(counts, btot);
    k_reorder<<<NCHUNK, 256, 0, stream>>>(ei, counts, btot, pairs);
    k_csr<<<NBUCKET, 256, 0, stream>>>(pairs, btot, rowg, degg, sorted_src);
    // layer-1 projection LAST before agg1 -> g1 warm in L2
    k1_xw<<<N_NODES / 16, 256, 0, stream>>>(x, W1, a1s, a1d, g1, e1d);
    // layer 1 aggregation + fused layer-2 projection -> packed g2 (LPN=8, U=16)
    k_agg<8, 16, 64, 32, false><<<(N_NODES * 8 + 255) / 256, 256, 0, stream>>>(
        rowg, degg, sorted_src, e1d, g1, b1, W2, a2s, a2d, g2, e2d,
        nullptr, nullptr, nullptr);
    // layer 2 aggregation + head (LPN=4, U=16; es2 packed inside g2 rows)
    k_agg<4, 16, 32, 16, true><<<(N_NODES * 4 + 255) / 256, 256, 0, stream>>>(
        rowg, degg, sorted_src, e2d, g2, b2, nullptr, nullptr, nullptr,
        nullptr, nullptr, Wf, bf, out);
}

// Round 13
// 268.419 us; speedup vs baseline: 1.0365x; 1.0365x over previous
//
#include <hip/hip_runtime.h>
#include <math.h>

#define N_NODES 100000
#define N_EDGES 3200000
#define E_TOT   (N_EDGES + N_NODES)
#define F_IN    128
#define H1      16
#define H2      8
#define NEG     0.2f
#define LOG2E   1.4426950408889634f
#define NBUCKET ((N_NODES + 255) >> 8)             // 391 buckets of 256 nodes
#define NCHUNK  512
#define CE      ((N_EDGES + NCHUNK - 1) / NCHUNK)  // 6250 edges per chunk

typedef _Float16 half2v __attribute__((ext_vector_type(2)));
typedef _Float16 half8v __attribute__((ext_vector_type(8)));

// ---- kernel 1: packed layer-1 gather table g1 (64B/node: 16 fp16 h ; fp32 es)
// es/ed pre-scaled by log2(e) so the agg hot loop uses exp2 directly ----
__global__ __launch_bounds__(256) void k1_xw(
        const float* __restrict__ x, const float* __restrict__ W1,
        const float* __restrict__ a1s, const float* __restrict__ a1d,
        char* __restrict__ g1, float* __restrict__ e1d) {
    __shared__ float w1s[F_IN * H1];     // 8 KB
    __shared__ float xs[16 * 132];       // padded stride 132 -> conflict-free
    __shared__ float a1ss[H1], a1ds[H1];
    const int tid = threadIdx.x;
    for (int i = tid; i < F_IN * H1; i += 256) w1s[i] = W1[i];
    if (tid < H1) { a1ss[tid] = a1s[tid]; a1ds[tid] = a1d[tid]; }
    const int rowbase = blockIdx.x * 16;
    #pragma unroll
    for (int i = 0; i < 2; i++) {
        int q = tid + i * 256;
        int r = q >> 5, c = q & 31;
        float4 v = *(const float4*)(x + (size_t)(rowbase + r) * F_IN + c * 4);
        *(float4*)(xs + r * 132 + c * 4) = v;
    }
    __syncthreads();
    const int g = tid >> 4, j = tid & 15;
    const float* xrow = xs + g * 132;
    float acc = 0.f;
    #pragma unroll 8
    for (int k = 0; k < F_IN; k++) acc += xrow[k] * w1s[k * H1 + j];
    const int row = rowbase + g;
    char* grow = g1 + (size_t)row * 64;
    ((_Float16*)grow)[j] = (_Float16)acc;
    float ps = acc * a1ss[j];
    float pd = acc * a1ds[j];
    #pragma unroll
    for (int m = 8; m >= 1; m >>= 1) {
        ps += __shfl_xor(ps, m, 16);
        pd += __shfl_xor(pd, m, 16);
    }
    if (j == 0) { *(float*)(grow + 32) = ps * LOG2E; e1d[row] = pd * LOG2E; }
}

// ---- counting-sort CSR build (no global atomics) ----

__global__ __launch_bounds__(256) void k_count(const int2* __restrict__ ei,
                                               int* __restrict__ counts) {
    __shared__ int hist[NBUCKET];
    for (int i = threadIdx.x; i < NBUCKET; i += 256) hist[i] = 0;
    __syncthreads();
    const int b = blockIdx.x;
    const int beg = b * CE, end = min(N_EDGES, beg + CE);
    for (int e = beg + threadIdx.x; e < end; e += 256)
        atomicAdd(&hist[ei[e].y >> 8], 1);
    __syncthreads();
    for (int i = threadIdx.x; i < NBUCKET; i += 256)
        counts[i * NCHUNK + b] = hist[i];
}

__global__ __launch_bounds__(512) void k_scanA(int* __restrict__ counts,
                                               int* __restrict__ btot) {
    __shared__ int lds[NCHUNK];
    const int k = blockIdx.x, t = threadIdx.x;
    int v = counts[k * NCHUNK + t];
    lds[t] = v;
    __syncthreads();
    for (int off = 1; off < NCHUNK; off <<= 1) {
        int u = (t >= off) ? lds[t - off] : 0;
        __syncthreads();
        lds[t] += u;
        __syncthreads();
    }
    counts[k * NCHUNK + t] = lds[t] - v;   // exclusive within bucket
    if (t == NCHUNK - 1) btot[k] = lds[t];
}

__global__ __launch_bounds__(512) void k_scanB(const int* __restrict__ btot,
                                               int* __restrict__ bbase) {
    __shared__ int lds[512];
    const int t = threadIdx.x;
    int v = (t < NBUCKET) ? btot[t] : 0;
    lds[t] = v;
    __syncthreads();
    for (int off = 1; off < 512; off <<= 1) {
        int u = (t >= off) ? lds[t - off] : 0;
        __syncthreads();
        lds[t] += u;
        __syncthreads();
    }
    if (t < NBUCKET) bbase[t] = lds[t] - v;
    if (t == 511) bbase[NBUCKET] = lds[511];   // == N_EDGES
}

__global__ __launch_bounds__(256) void k_reorder(const int2* __restrict__ ei,
                                                 const int* __restrict__ counts,
                                                 const int* __restrict__ bbase,
                                                 int* __restrict__ pairs) {
    __shared__ int cur[NBUCKET];
    const int b = blockIdx.x;
    for (int i = threadIdx.x; i < NBUCKET; i += 256)
        cur[i] = bbase[i] + counts[i * NCHUNK + b];
    __syncthreads();
    const int beg = b * CE, end = min(N_EDGES, beg + CE);
    for (int e = beg + threadIdx.x; e < end; e += 256) {
        int2 v = ei[e];
        int k = v.y >> 8;
        int pos = atomicAdd(&cur[k], 1);      // LDS atomic only
        pairs[pos] = (v.x << 8) | (v.y & 255);
    }
}

__global__ __launch_bounds__(256) void k_csr(const int* __restrict__ pairs,
                                             const int* __restrict__ bbase,
                                             int* __restrict__ rowg,
                                             int* __restrict__ degg,
                                             int* __restrict__ sorted_src) {
    __shared__ int deg[256], scn[256], cur[256];
    const int k = blockIdx.x, t = threadIdx.x;
    const int n0 = k << 8;
    const int nn = min(256, N_NODES - n0);
    deg[t] = 0;
    __syncthreads();
    const int ebeg = bbase[k], eend = bbase[k + 1];
    for (int e = ebeg + t; e < eend; e += 256)
        atomicAdd(&deg[pairs[e] & 255], 1);
    __syncthreads();
    int v = (t < nn) ? deg[t] : 0;
    scn[t] = v;
    __syncthreads();
    for (int off = 1; off < 256; off <<= 1) {
        int u = (t >= off) ? scn[t - off] : 0;
        __syncthreads();
        scn[t] += u;
        __syncthreads();
    }
    int excl = scn[t] - v;
    if (t < nn) {
        int r = ebeg + excl + n0 + t;   // + self-loops of all preceding nodes
        rowg[n0 + t] = r;
        degg[n0 + t] = v + 1;
        sorted_src[r] = n0 + t;         // self-loop occupies slot 0
        cur[t] = r + 1;
    }
    __syncthreads();
    for (int e = ebeg + t; e < eend; e += 256) {
        int p = pairs[e];
        int pos = atomicAdd(&cur[p & 255], 1);   // LDS atomic only
        sorted_src[pos] = p >> 8;
    }
}

// ---- node-parallel softmax aggregation over packed gather tables ----
// (FROZEN: measured 41.1us agg1 in R8. One random 64B line per edge; U=16
// outstanding gathers; log2e-prescaled logits -> exp2.)
template <int LPN, int U, int ROWB, int ESOFF, bool LAYER2>
__global__ __launch_bounds__(256) void k_agg(
        const int* __restrict__ row, const int* __restrict__ deg,
        const int* __restrict__ sorted_src,
        const float* __restrict__ ed, const char* __restrict__ gtab,
        const float* __restrict__ b,
        const float* __restrict__ W2, const float* __restrict__ a2s,
        const float* __restrict__ a2d,
        char* __restrict__ g2out, float* __restrict__ e2d_out,
        const float* __restrict__ Wf, const float* __restrict__ bf,
        float* __restrict__ out) {
    __shared__ float w2s[H1 * H2];
    __shared__ float a2ss[H2], a2ds[H2];
    if (!LAYER2) {
        for (int i = threadIdx.x; i < H1 * H2; i += 256) w2s[i] = W2[i];
        if (threadIdx.x < H2) { a2ss[threadIdx.x] = a2s[threadIdx.x];
                                a2ds[threadIdx.x] = a2d[threadIdx.x]; }
        __syncthreads();
    }
    const int sub = threadIdx.x & (LPN - 1);
    const int node = (blockIdx.x * 256 + threadIdx.x) / LPN;
    if (node >= N_NODES) return;
    const int beg = row[node];
    const int cnt = deg[node];            // >= 1 (self-loop)
    const float edv = ed[node];           // pre-scaled by log2(e)
    float2 acc = make_float2(0.f, 0.f);
    float s = 0.f;
    int srcs[U];
    #pragma unroll
    for (int i = 0; i < U; i++) srcs[i] = sorted_src[beg + (i < cnt ? i : 0)];
    for (int t0 = 0; t0 < cnt; t0 += U) {
        float evs[U];
        half2v hvs[U];
        // issue gathers for the current batch (one 64B line per edge)
        #pragma unroll
        for (int i = 0; i < U; i++) {
            const char* rp = gtab + (unsigned)srcs[i] * ROWB;
            hvs[i] = *(const half2v*)(rp + sub * 4);
            evs[i] = *(const float*)(rp + ESOFF);   // same line as h -> free
        }
        // prefetch next batch's indices while gathers are in flight
        int nsrcs[U];
        #pragma unroll
        for (int i = 0; i < U; i++) {
            int idx = t0 + U + i;
            nsrcs[i] = sorted_src[beg + (idx < cnt ? idx : 0)];
        }
        #pragma unroll
        for (int i = 0; i < U; i++) {
            if (t0 + i < cnt) {
                float k = evs[i] + edv;
                k = fmaxf(k, NEG * k);              // leaky_relu (scale-invariant)
                float p = __builtin_amdgcn_exp2f(k);
                s += p;
                acc.x += p * (float)hvs[i].x;
                acc.y += p * (float)hvs[i].y;
            }
        }
        #pragma unroll
        for (int i = 0; i < U; i++) srcs[i] = nsrcs[i];
    }
    const float inv = 1.f / s;
    const float2 bv = ((const float2*)b)[sub];
    float2 o;
    o.x = fmaxf(acc.x * inv + bv.x, 0.f);
    o.y = fmaxf(acc.y * inv + bv.y, 0.f);
    if (!LAYER2) {
        // fused h2 = relu(h1) @ W2 ; e2s ; e2d  (lane sub owns h1 rows 2sub, 2sub+1)
        float p2[H2];
        const float* w0 = w2s + (2 * sub) * H2;
        const float* w1 = w2s + (2 * sub + 1) * H2;
        #pragma unroll
        for (int i = 0; i < H2; i++) p2[i] = o.x * w0[i] + o.y * w1[i];
        #pragma unroll
        for (int i = 0; i < H2; i++) {
            p2[i] += __shfl_xor(p2[i], 1);
            p2[i] += __shfl_xor(p2[i], 2);
            p2[i] += __shfl_xor(p2[i], 4);
        }
        float es2 = 0.f, ed2 = 0.f;
        #pragma unroll
        for (int i = 0; i < H2; i++) { es2 += p2[i] * a2ss[i]; ed2 += p2[i] * a2ds[i]; }
        char* orow = g2out + (size_t)node * 32;
        if (sub == 0) {
            half8v h8;
            #pragma unroll
            for (int i = 0; i < H2; i++) h8[i] = (_Float16)p2[i];
            *(half8v*)orow = h8;                      // bytes 0..15
        } else if (sub == 1) {
            *(float*)(orow + 16) = es2 * LOG2E;       // es2 in the same 32B row
        } else if (sub == 2) {
            e2d_out[node] = ed2 * LOG2E;
        }
    } else {
        // final head: out = relu(h2agg) . Wf + bf  (lane sub owns h2 2sub, 2sub+1)
        const float2 wv = ((const float2*)Wf)[sub];
        float r = o.x * wv.x + o.y * wv.y;
        r += __shfl_xor(r, 1);
        r += __shfl_xor(r, 2);
        if (sub == 0) out[node] = r + bf[0];
    }
}

extern "C" void kernel_launch(void* const* d_in, const int* in_sizes, int n_in,
                              void* d_out, int out_size, void* d_ws, size_t ws_size,
                              hipStream_t stream) {
    const float* x    = (const float*)d_in[0];
    const int2*  ei   = (const int2*)d_in[1];   // int32 pairs [src,dst]
    const float* W1   = (const float*)d_in[2];
    const float* a1s  = (const float*)d_in[3];
    const float* a1d  = (const float*)d_in[4];
    const float* b1   = (const float*)d_in[5];
    const float* W2   = (const float*)d_in[6];
    const float* a2s  = (const float*)d_in[7];
    const float* a2d  = (const float*)d_in[8];
    const float* b2   = (const float*)d_in[9];
    const float* Wf   = (const float*)d_in[10];
    const float* bf   = (const float*)d_in[11];
    float* out = (float*)d_out;

    // workspace layout; pairs region (12.8 MB) is dead after k_csr and hosts
    // all post-CSR tables: g2 3.2 + e2d 0.4; g1 (6.4) + e1d live separately
    char* wp = (char*)d_ws;
    int* sorted_src = (int*)wp;   wp += sizeof(int) * (size_t)E_TOT;
    char* pairs_region = wp;      wp += sizeof(int) * (size_t)N_EDGES;   // 12.8 MB
    int* counts     = (int*)wp;   wp += sizeof(int) * (size_t)NBUCKET * NCHUNK;
    int* btot       = (int*)wp;   wp += sizeof(int) * (NBUCKET + 1);
    int* bbase      = (int*)wp;   wp += sizeof(int) * (NBUCKET + 1);
    int* degg       = (int*)wp;   wp += sizeof(int) * N_NODES;
    int* rowg       = (int*)wp;   wp += sizeof(int) * N_NODES;
    char* g1        = wp;         wp += (size_t)64 * N_NODES;            // 6.4 MB
    float* e1d      = (float*)wp; wp += sizeof(float) * N_NODES;

    int*   pairs = (int*)pairs_region;
    char*  g2    = pairs_region;                              // 32B * N = 3.2 MB
    float* e2d   = (float*)(g2 + (size_t)32 * N_NODES);       // 0.4 MB

    // CSR build (atomic-free w.r.t. global memory)
    k_count<<<NCHUNK, 256, 0, stream>>>(ei, counts);
    k_scanA<<<NBUCKET, 512, 0, stream>>>(counts, btot);
    k_scanB<<<1, 512, 0, stream>>>(btot, bbase);
    k_reorder<<<NCHUNK, 256, 0, stream>>>(ei, counts, bbase, pairs);
    k_csr<<<NBUCKET, 256, 0, stream>>>(pairs, bbase, rowg, degg, sorted_src);
    // layer 1 projection -> packed g1 (64B rows: h1 + es1)
    k1_xw<<<N_NODES / 16, 256, 0, stream>>>(x, W1, a1s, a1d, g1, e1d);
    // layer 1 aggregation + fused layer-2 projection -> packed g2 (LPN=8, U=16)
    k_agg<8, 16, 64, 32, false><<<(N_NODES * 8 + 255) / 256, 256, 0, stream>>>(
        rowg, degg, sorted_src, e1d, g1, b1, W2, a2s, a2d, g2, e2d,
        nullptr, nullptr, nullptr);
    // layer 2 aggregation + head (LPN=4, U=16; es2 packed inside g2 rows)
    k_agg<4, 16, 32, 16, true><<<(N_NODES * 4 + 255) / 256, 256, 0, stream>>>(
        rowg, degg, sorted_src, e2d, g2, b2, nullptr, nullptr, nullptr,
        nullptr, nullptr, Wf, bf, out);
}